// Round 1
// baseline (1269.269 us; speedup 1.0000x reference)
//
#include <hip/hip_runtime.h>
#include <math.h>

#define N 256
#define VOL (N * N * N)          // 16777216
#define SPAD 224
#define NSHELL 222
#define PI_D 3.14159265358979323846

// ---- twiddle table: tw[k] = exp(-2*pi*i*k/256), computed in f64 for accuracy ----
__device__ __forceinline__ void make_twiddles(float* twr, float* twi, int t) {
  if (t < 128) {
    double a = -2.0 * PI_D * (double)t / 256.0;
    twr[t] = (float)cos(a);
    twi[t] = (float)sin(a);
  }
}

// ---- Pass 1: pack Z = X + iY and FFT along z (contiguous). 4 lines/block. ----
__global__ __launch_bounds__(256) void fft_z_pack(const float* __restrict__ X,
                                                  const float* __restrict__ Y,
                                                  float* __restrict__ Zr,
                                                  float* __restrict__ Zi) {
  __shared__ float dr[4 * 256], di[4 * 256];
  __shared__ float twr[128], twi[128];
  int t = threadIdx.x;
  make_twiddles(twr, twi, t);
  int line = t >> 6, l = t & 63;
  size_t L = (size_t)blockIdx.x * 4 + line;   // 0..65535 line index (x*256+y)
  const float* xp = X + L * 256;
  const float* yp = Y + L * 256;
  float* sr = dr + line * 256;
  float* si = di + line * 256;
#pragma unroll
  for (int k = 0; k < 4; ++k) {
    int e = l + 64 * k;
    int r = __brev((unsigned)e) >> 24;        // bit-reversed load for DIT
    sr[r] = xp[e];
    si[r] = yp[e];
  }
  __syncthreads();
#pragma unroll
  for (int s = 0; s < 8; ++s) {
    int half = 1 << s;
#pragma unroll
    for (int k = 0; k < 2; ++k) {
      int j = l + 64 * k;                     // butterfly 0..127
      int p = j & (half - 1);
      int i0 = ((j >> s) << (s + 1)) + p;
      int i1 = i0 + half;
      int ti = p << (7 - s);
      float wr = twr[ti], wi = twi[ti];
      float ar = sr[i0], ai = si[i0];
      float br = sr[i1], bi = si[i1];
      float cr = br * wr - bi * wi;
      float ci = br * wi + bi * wr;
      sr[i0] = ar + cr; si[i0] = ai + ci;
      sr[i1] = ar - cr; si[i1] = ai - ci;
    }
    __syncthreads();
  }
  float* zr = Zr + L * 256;
  float* zi = Zi + L * 256;
#pragma unroll
  for (int k = 0; k < 4; ++k) {
    int e = l + 64 * k;
    zr[e] = sr[e];
    zi[e] = si[e];
  }
}

// ---- Pass 2/3: FFT along a strided axis. Tile = 16 z-consecutive lines. ----
// y-pass: estride=256,   histride=65536 (hi = x)
// x-pass: estride=65536, histride=256   (hi = y)
__global__ __launch_bounds__(256) void fft_strided(float* __restrict__ Zr,
                                                   float* __restrict__ Zi,
                                                   int estride, int histride) {
  __shared__ float dr[256 * 16], di[256 * 16];   // layout [elem*16 + line]
  __shared__ float twr[128], twi[128];
  int t = threadIdx.x;
  make_twiddles(twr, twi, t);
  int z = t & 15, c = t >> 4;
  int hi = blockIdx.x >> 4, lo = blockIdx.x & 15;
  size_t base = (size_t)hi * (size_t)histride + (size_t)lo * 16 + (size_t)z;
#pragma unroll
  for (int i = 0; i < 16; ++i) {
    int e = c * 16 + i;
    int r = __brev((unsigned)e) >> 24;
    size_t g = base + (size_t)e * (size_t)estride;
    dr[r * 16 + z] = Zr[g];
    di[r * 16 + z] = Zi[g];
  }
  __syncthreads();
  for (int s = 0; s < 8; ++s) {
    int half = 1 << s;
#pragma unroll
    for (int k = 0; k < 8; ++k) {
      int j = c + 16 * k;                     // butterfly 0..127
      int p = j & (half - 1);
      int i0 = ((j >> s) << (s + 1)) + p;
      int i1 = i0 + half;
      int ti = p << (7 - s);
      float wr = twr[ti], wi = twi[ti];
      int a0 = i0 * 16 + z, a1 = i1 * 16 + z;
      float ar = dr[a0], ai = di[a0];
      float br = dr[a1], bi = di[a1];
      float cr = br * wr - bi * wi;
      float ci = br * wi + bi * wr;
      dr[a0] = ar + cr; di[a0] = ai + ci;
      dr[a1] = ar - cr; di[a1] = ai - ci;
    }
    __syncthreads();
  }
#pragma unroll
  for (int i = 0; i < 16; ++i) {
    int e = c * 16 + i;
    size_t g = base + (size_t)e * (size_t)estride;
    Zr[g] = dr[e * 16 + z];
    Zi[g] = di[e * 16 + z];
  }
}

// ---- Pass 4: unpack Fx,Fy via Hermitian symmetry, shell-accumulate. ----
__global__ __launch_bounds__(256) void reduce_shells(const float* __restrict__ Zr,
                                                     const float* __restrict__ Zi,
                                                     double* __restrict__ sums) {
  __shared__ float sh[3 * SPAD];
  int t = threadIdx.x;
  for (int i = t; i < 3 * SPAD; i += 256) sh[i] = 0.f;
  __syncthreads();
  int stride = gridDim.x * 256;
  for (int idx = blockIdx.x * 256 + t; idx < VOL; idx += stride) {
    int x = idx >> 16, y = (idx >> 8) & 255, zz = idx & 255;
    int fx = x - ((x & 128) ? 256 : 0);
    int fy = y - ((y & 128) ? 256 : 0);
    int fz = zz - ((zz & 128) ? 256 : 0);
    int m = fx * fx + fy * fy + fz * fz;       // integer, <= 49152
    int nidx = (((256 - x) & 255) << 16) | (((256 - y) & 255) << 8) | ((256 - zz) & 255);
    float Ar = Zr[idx], Ai = Zi[idx];          // Z(k)
    float Br = Zr[nidx], Bi = Zi[nidx];        // Z(-k)
    float fxr = 0.5f * (Ar + Br), fxi = 0.5f * (Ai - Bi);
    float fyr = 0.5f * (Ai + Bi), fyi = 0.5f * (Br - Ar);
    float nu = fxr * fyr + fxi * fyi;
    float px = fxr * fxr + fxi * fxi;
    float py = fyr * fyr + fyi * fyi;
    // exact integer isqrt -> bin (matches floor(sqrt(f64)) of the reference)
    int sb = (int)sqrtf((float)m);
    if (sb > 221) sb = 221;
    while (sb * sb > m) --sb;
    while ((sb + 1) * (sb + 1) <= m) ++sb;
    atomicAdd(&sh[sb], nu);
    atomicAdd(&sh[SPAD + sb], px);
    atomicAdd(&sh[2 * SPAD + sb], py);
  }
  __syncthreads();
  for (int i = t; i < 3 * SPAD; i += 256) atomicAdd(&sums[i], (double)sh[i]);
}

// ---- Final: fsc = num / sqrt(px*py + eps), mean over (2 batches x 222 shells) ----
__global__ void finalize(const double* __restrict__ sums, float* __restrict__ out) {
  if (threadIdx.x == 0 && blockIdx.x == 0) {
    double acc = 0.0;
    for (int b = 0; b < 2; ++b) {
      const double* s = sums + b * 3 * SPAD;
      for (int k = 0; k < NSHELL; ++k) {
        double nu = s[k];
        double px = s[SPAD + k];
        double py = s[2 * SPAD + k];
        acc += nu / sqrt(px * py + 1e-8);
      }
    }
    out[0] = (float)(acc / (2.0 * (double)NSHELL));
  }
}

extern "C" void kernel_launch(void* const* d_in, const int* in_sizes, int n_in,
                              void* d_out, int out_size, void* d_ws, size_t ws_size,
                              hipStream_t stream) {
  const float* X = (const float*)d_in[0];   // (2,1,256,256,256) f32
  const float* Y = (const float*)d_in[1];
  float* Zr = (float*)d_ws;                                   // VOL floats
  float* Zi = Zr + VOL;                                       // VOL floats
  double* sums = (double*)((char*)d_ws + (size_t)2 * VOL * 4); // 2*3*SPAD doubles

  hipMemsetAsync(sums, 0, 2 * 3 * SPAD * sizeof(double), stream);

  for (int b = 0; b < 2; ++b) {
    const float* Xb = X + (size_t)b * VOL;
    const float* Yb = Y + (size_t)b * VOL;
    fft_z_pack<<<VOL / 256 / 4, 256, 0, stream>>>(Xb, Yb, Zr, Zi);
    fft_strided<<<4096, 256, 0, stream>>>(Zr, Zi, 256, 65536);   // FFT along y
    fft_strided<<<4096, 256, 0, stream>>>(Zr, Zi, 65536, 256);   // FFT along x
    reduce_shells<<<4096, 256, 0, stream>>>(Zr, Zi, sums + b * 3 * SPAD);
  }
  finalize<<<1, 64, 0, stream>>>(sums, (float*)d_out);
}

// Round 2
// 1238.861 us; speedup vs baseline: 1.0245x; 1.0245x over previous
//
#include <hip/hip_runtime.h>
#include <math.h>

#define VOL (256 * 256 * 256)
#define NSHELL 222
#define SBINS 224
#define PI_D 3.14159265358979323846

// base-4 digit reversal of an 8-bit index
__device__ __forceinline__ int rev4(int e) {
  return ((e & 3) << 6) | (((e >> 2) & 3) << 4) | (((e >> 4) & 3) << 2) | ((e >> 6) & 3);
}

__device__ __forceinline__ void fill_tw(float* twr, float* twi, int t) {
  if (t < 256) {
    double a = -2.0 * PI_D * (double)t / 256.0;
    twr[t] = (float)cos(a);
    twi[t] = (float)sin(a);
  }
}

// radix-4 DIT butterfly on 4 LDS slots a[0..3]; twiddle W_256^{q*p*tfac}
__device__ __forceinline__ void bfly4(float* re, float* im, const float* twr,
                                      const float* twi, const int* a, int p, int tfac) {
  float br[4], bi[4];
  br[0] = re[a[0]]; bi[0] = im[a[0]];
#pragma unroll
  for (int q = 1; q < 4; ++q) {
    float xr = re[a[q]], xi = im[a[q]];
    int ti = (q * p * tfac) & 255;
    float wr = twr[ti], wi = twi[ti];
    br[q] = xr * wr - xi * wi;
    bi[q] = xr * wi + xi * wr;
  }
  float t0r = br[0] + br[2], t0i = bi[0] + bi[2];
  float t1r = br[0] - br[2], t1i = bi[0] - bi[2];
  float t2r = br[1] + br[3], t2i = bi[1] + bi[3];
  float t3r = br[1] - br[3], t3i = bi[1] - bi[3];
  float u3r = t3i, u3i = -t3r;                       // -i * t3
  re[a[0]] = t0r + t2r; im[a[0]] = t0i + t2i;
  re[a[1]] = t1r + u3r; im[a[1]] = t1i + u3i;
  re[a[2]] = t0r - t2r; im[a[2]] = t0i - t2i;
  re[a[3]] = t1r - u3r; im[a[3]] = t1i - u3i;
}

// ---- Pass 1: pack Z = X + iY, radix-4 FFT along z (contiguous). 4 lines/block ----
__global__ __launch_bounds__(256) void fft_z_pack(const float* __restrict__ X,
                                                  const float* __restrict__ Y,
                                                  float2* __restrict__ Z) {
  __shared__ float sr[4 * 264], si[4 * 264];   // pad: a + (a>>5)
  __shared__ float twr[256], twi[256];
  int t = threadIdx.x;
  fill_tw(twr, twi, t);
  int line = t >> 6, l = t & 63;
  size_t L = (size_t)blockIdx.x * 4 + line;
  const float4* xp = (const float4*)(X + L * 256);
  const float4* yp = (const float4*)(Y + L * 256);
  float* pr = sr + line * 264;
  float* pim = si + line * 264;
  float4 xv = xp[l], yv = yp[l];
  {
    float xs[4] = {xv.x, xv.y, xv.z, xv.w};
    float ys[4] = {yv.x, yv.y, yv.z, yv.w};
#pragma unroll
    for (int q = 0; q < 4; ++q) {
      int e = 4 * l + q;
      int r = rev4(e);
      int pa = r + (r >> 5);
      pr[pa] = xs[q];
      pim[pa] = ys[q];
    }
  }
  __syncthreads();
#pragma unroll
  for (int s = 0; s < 4; ++s) {
    int s2 = 2 * s, quarter = 1 << s2, tfac = 64 >> s2;
    int j = l, p = j & (quarter - 1);
    int i0 = ((j >> s2) << (s2 + 2)) + p;
    int a[4];
#pragma unroll
    for (int q = 0; q < 4; ++q) { int aa = i0 + q * quarter; a[q] = aa + (aa >> 5); }
    bfly4(pr, pim, twr, twi, a, p, tfac);
    __syncthreads();
  }
  float2* zp = Z + L * 256;
#pragma unroll
  for (int k = 0; k < 4; ++k) {
    int e = l + 64 * k;
    int pa = e + (e >> 5);
    zp[e] = make_float2(pr[pa], pim[pa]);
  }
}

// ---- Pass 2: radix-4 FFT along y. Tile = 16 z x 256 y at fixed x. ----
__global__ __launch_bounds__(256) void fft_y(float2* __restrict__ Z) {
  __shared__ float sr[4352], si[4352];        // [e*17 + zi]
  __shared__ float twr[256], twi[256];
  int t = threadIdx.x;
  fill_tw(twr, twi, t);
  int zi = t & 15, c = t >> 4;                // c 0..15
  int x = blockIdx.x >> 4, lo = blockIdx.x & 15;
  size_t base = (size_t)x * 65536 + (size_t)(lo * 16 + zi);
#pragma unroll
  for (int i = 0; i < 16; ++i) {
    int e = c * 16 + i;
    int r = rev4(e);
    float2 v = Z[base + (size_t)e * 256];
    sr[r * 17 + zi] = v.x;
    si[r * 17 + zi] = v.y;
  }
  __syncthreads();
#pragma unroll
  for (int s = 0; s < 4; ++s) {
    int s2 = 2 * s, quarter = 1 << s2, tfac = 64 >> s2;
#pragma unroll
    for (int ib = 0; ib < 4; ++ib) {
      int j = c + 16 * ib, p = j & (quarter - 1);
      int i0 = ((j >> s2) << (s2 + 2)) + p;
      int a[4];
#pragma unroll
      for (int q = 0; q < 4; ++q) a[q] = (i0 + q * quarter) * 17 + zi;
      bfly4(sr, si, twr, twi, a, p, tfac);
    }
    __syncthreads();
  }
#pragma unroll
  for (int i = 0; i < 16; ++i) {
    int e = c * 16 + i;
    Z[base + (size_t)e * 256] = make_float2(sr[e * 17 + zi], si[e * 17 + zi]);
  }
}

// ---- Pass 3: radix-4 FFT along x + fused Hermitian unpack + shell reduce. ----
// Block = (y, lo): tile A = all x, z in [8lo, 8lo+8), y.  tile B = mirror tile:
// y' = (-y)&255, z' window = (249-8lo+zi)&255 so that mirror of (x, zA=8lo+i)
// is tile B slot (x'=(-x)&255, j=7-i).  Never writes Z back.
__global__ __launch_bounds__(512) void fft_x_reduce(const float2* __restrict__ Z,
                                                    double* __restrict__ sums) {
  __shared__ float sAr[2304], sAi[2304], sBr[2304], sBi[2304];  // [e*9 + zi]
  __shared__ float twr[256], twi[256];
  __shared__ float sh[3 * SBINS];
  int t = threadIdx.x;
  fill_tw(twr, twi, t);
  for (int i = t; i < 3 * SBINS; i += 512) sh[i] = 0.f;
  int y = blockIdx.x >> 5, lo = blockIdx.x & 31;
  int tile = t >> 8, tt = t & 255, zi = tt & 7, c = tt >> 3;   // c 0..31
  float* pr = tile ? sBr : sAr;
  float* pim = tile ? sBi : sAi;
  int yy = tile ? ((256 - y) & 255) : y;
  int zz = tile ? ((249 - 8 * lo + zi) & 255) : (8 * lo + zi);
  size_t base = (size_t)yy * 256 + (size_t)zz;
#pragma unroll
  for (int i = 0; i < 8; ++i) {
    int e = c * 8 + i;
    int r = rev4(e);
    float2 v = Z[base + (size_t)e * 65536];
    pr[r * 9 + zi] = v.x;
    pim[r * 9 + zi] = v.y;
  }
  __syncthreads();
#pragma unroll
  for (int s = 0; s < 4; ++s) {
    int s2 = 2 * s, quarter = 1 << s2, tfac = 64 >> s2;
#pragma unroll
    for (int ib = 0; ib < 2; ++ib) {
      int j = c + 32 * ib, p = j & (quarter - 1);
      int i0 = ((j >> s2) << (s2 + 2)) + p;
      int a[4];
#pragma unroll
      for (int q = 0; q < 4; ++q) a[q] = (i0 + q * quarter) * 9 + zi;
      bfly4(pr, pim, twr, twi, a, p, tfac);
    }
    __syncthreads();
  }
  int fy = y - ((y & 128) ? 256 : 0);
#pragma unroll
  for (int it = 0; it < 4; ++it) {
    int v = t + 512 * it;            // 2048 tile-A voxels per block
    int x = v & 255, i = v >> 8;
    int z = 8 * lo + i;
    int fx = x - ((x & 128) ? 256 : 0);
    int fz = z - ((z & 128) ? 256 : 0);
    int m = fx * fx + fy * fy + fz * fz;
    int sb = (int)sqrtf((float)m);
    while (sb * sb > m) --sb;
    while ((sb + 1) * (sb + 1) <= m) ++sb;
    int aA = x * 9 + i;
    float Ar = sAr[aA], Ai = sAi[aA];            // Z(k)
    int xm = (256 - x) & 255;
    int aB = xm * 9 + (7 - i);
    float Br = sBr[aB], Bi = sBi[aB];            // Z(-k)
    float fxr = 0.5f * (Ar + Br), fxi = 0.5f * (Ai - Bi);
    float fyr = 0.5f * (Ai + Bi), fyi = 0.5f * (Br - Ar);
    atomicAdd(&sh[3 * sb + 0], fxr * fyr + fxi * fyi);
    atomicAdd(&sh[3 * sb + 1], fxr * fxr + fxi * fxi);
    atomicAdd(&sh[3 * sb + 2], fyr * fyr + fyi * fyi);
  }
  __syncthreads();
  for (int i = t; i < 3 * SBINS; i += 512) atomicAdd(&sums[i], (double)sh[i]);
}

__global__ void finalize(const double* __restrict__ sums, float* __restrict__ out) {
  if (threadIdx.x == 0 && blockIdx.x == 0) {
    double acc = 0.0;
    for (int b = 0; b < 2; ++b) {
      const double* s = sums + b * 3 * SBINS;
      for (int k = 0; k < NSHELL; ++k)
        acc += s[3 * k] / sqrt(s[3 * k + 1] * s[3 * k + 2] + 1e-8);
    }
    out[0] = (float)(acc / (2.0 * (double)NSHELL));
  }
}

extern "C" void kernel_launch(void* const* d_in, const int* in_sizes, int n_in,
                              void* d_out, int out_size, void* d_ws, size_t ws_size,
                              hipStream_t stream) {
  const float* X = (const float*)d_in[0];
  const float* Y = (const float*)d_in[1];
  float2* Z = (float2*)d_ws;                                  // VOL complex floats
  double* sums = (double*)((char*)d_ws + (size_t)VOL * 8);    // 2*3*SBINS doubles

  hipMemsetAsync(sums, 0, 2 * 3 * SBINS * sizeof(double), stream);

  for (int b = 0; b < 2; ++b) {
    fft_z_pack<<<VOL / 1024, 256, 0, stream>>>(X + (size_t)b * VOL, Y + (size_t)b * VOL, Z);
    fft_y<<<4096, 256, 0, stream>>>(Z);
    fft_x_reduce<<<8192, 512, 0, stream>>>(Z, sums + b * 3 * SBINS);
  }
  finalize<<<1, 1, 0, stream>>>(sums, (float*)d_out);
}

// Round 3
// 878.885 us; speedup vs baseline: 1.4442x; 1.4096x over previous
//
#include <hip/hip_runtime.h>
#include <math.h>

#define VOL (256 * 256 * 256)
#define NSHELL 222
#define SBINS 224
#define PI_D 3.14159265358979323846
#define VSTRIDE ((size_t)129 << 16)   // one half-volume: 129 planes of 256x256 float2

// base-4 digit reversal of an 8-bit index (self-inverse)
__device__ __forceinline__ int rev4(int e) {
  return ((e & 3) << 6) | (((e >> 2) & 3) << 4) | (((e >> 4) & 3) << 2) | ((e >> 6) & 3);
}

__device__ __forceinline__ void fill_tw(float* twr, float* twi, int t) {
  if (t < 256) {
    double a = -2.0 * PI_D * (double)t / 256.0;
    twr[t] = (float)cos(a);
    twi[t] = (float)sin(a);
  }
}

// radix-4 DIF butterfly, in-place on 4 LDS slots; twiddles applied on outputs.
__device__ __forceinline__ void bfly4_dif(float* re, float* im, const float* twr,
                                          const float* twi, int a0, int a1, int a2,
                                          int a3, int t1, int t2, int t3) {
  float x0r = re[a0], x0i = im[a0], x1r = re[a1], x1i = im[a1];
  float x2r = re[a2], x2i = im[a2], x3r = re[a3], x3i = im[a3];
  float s02r = x0r + x2r, s02i = x0i + x2i, d02r = x0r - x2r, d02i = x0i - x2i;
  float s13r = x1r + x3r, s13i = x1i + x3i, d13r = x1r - x3r, d13i = x1i - x3i;
  re[a0] = s02r + s13r; im[a0] = s02i + s13i;
  float c1r = d02r + d13i, c1i = d02i - d13r;          // d02 - i*d13
  re[a1] = c1r * twr[t1] - c1i * twi[t1]; im[a1] = c1r * twi[t1] + c1i * twr[t1];
  float c2r = s02r - s13r, c2i = s02i - s13i;
  re[a2] = c2r * twr[t2] - c2i * twi[t2]; im[a2] = c2r * twi[t2] + c2i * twr[t2];
  float c3r = d02r - d13i, c3i = d02i + d13r;          // d02 + i*d13
  re[a3] = c3r * twr[t3] - c3i * twi[t3]; im[a3] = c3r * twi[t3] + c3i * twr[t3];
}

// ---- Pass 1: pack Z = X + iY, radix-4 DIF FFT along z, unpack Hermitian pair
// within the line (kz <-> -kz), write Fxz/Fyz for kz in [0,128], plane-major.
// Block: 16 z-lines (fixed y, x = x0..x0+15), 256 threads.
__global__ __launch_bounds__(256) void fft_z_pack(const float* __restrict__ X,
                                                  const float* __restrict__ Y,
                                                  float2* __restrict__ Gx,
                                                  float2* __restrict__ Gy) {
  __shared__ float zr[256 * 17], zi[256 * 17];   // [slot*17 + line]
  __shared__ float twr[256], twi[256];
  int t = threadIdx.x;
  fill_tw(twr, twi, t);
  int li = t >> 4, c = t & 15;
  int y = blockIdx.x >> 4;
  int x0 = (blockIdx.x & 15) << 4;
  const float4* xp = (const float4*)(X + (((size_t)(x0 + li)) << 16) + ((size_t)y << 8));
  const float4* yp = (const float4*)(Y + (((size_t)(x0 + li)) << 16) + ((size_t)y << 8));
#pragma unroll
  for (int it = 0; it < 4; ++it) {
    int e4 = c + 16 * it;
    float4 a = xp[e4];
    float4 b = yp[e4];
    int e = e4 << 2;
    zr[(e + 0) * 17 + li] = a.x; zi[(e + 0) * 17 + li] = b.x;
    zr[(e + 1) * 17 + li] = a.y; zi[(e + 1) * 17 + li] = b.y;
    zr[(e + 2) * 17 + li] = a.z; zi[(e + 2) * 17 + li] = b.z;
    zr[(e + 3) * 17 + li] = a.w; zi[(e + 3) * 17 + li] = b.w;
  }
  __syncthreads();
#pragma unroll
  for (int s = 0; s < 4; ++s) {
    int M = 64 >> (2 * s);
    int F = 1 << (2 * s);
#pragma unroll
    for (int ib = 0; ib < 4; ++ib) {
      int j = c + 16 * ib;
      int p = j & (M - 1);
      int jb = j >> (6 - 2 * s);
      int base = jb * (M << 2) + p;
      bfly4_dif(zr, zi, twr, twi, base * 17 + li, (base + M) * 17 + li,
                (base + 2 * M) * 17 + li, (base + 3 * M) * 17 + li,
                (p * F) & 255, (2 * p * F) & 255, (3 * p * F) & 255);
    }
    __syncthreads();
  }
  // slot s holds Z_fft[rev4(s)]; unpack kz and (256-kz)
  int krow = t >> 4, xi = t & 15;
#pragma unroll
  for (int g = 0; g < 9; ++g) {
    int kz = g * 16 + krow;
    if (kz <= 128) {
      int s1 = rev4(kz & 255);
      int s2 = rev4((256 - kz) & 255);
      float ar = zr[s1 * 17 + xi], ai = zi[s1 * 17 + xi];
      float br = zr[s2 * 17 + xi], bi = zi[s2 * 17 + xi];
      size_t off = ((size_t)kz << 16) + ((size_t)y << 8) + (size_t)(x0 + xi);
      Gx[off] = make_float2(0.5f * (ar + br), 0.5f * (ai - bi));
      Gy[off] = make_float2(0.5f * (ai + bi), 0.5f * (br - ar));
    }
  }
}

// ---- Pass 2: radix-4 DIF FFT along y, per kz-plane, per volume.
// Tile: 16 x (window) x 256 y. Leaves row r holding F[ ky = rev4(r) ].
__global__ __launch_bounds__(256) void fft_y(float2* __restrict__ G) {
  __shared__ float sr[256 * 17], si[256 * 17];   // [slot*17 + xi]
  __shared__ float twr[256], twi[256];
  int t = threadIdx.x;
  fill_tw(twr, twi, t);
  int xi = t & 15, c = t >> 4;
  int x0 = blockIdx.x << 4;
  int kz = blockIdx.y;
  float2* Gp = G + (size_t)blockIdx.z * VSTRIDE + ((size_t)kz << 16) + (size_t)(x0 + xi);
#pragma unroll
  for (int i = 0; i < 16; ++i) {
    int e = c * 16 + i;
    float2 v = Gp[(size_t)e << 8];
    sr[e * 17 + xi] = v.x;
    si[e * 17 + xi] = v.y;
  }
  __syncthreads();
#pragma unroll
  for (int s = 0; s < 4; ++s) {
    int M = 64 >> (2 * s);
    int F = 1 << (2 * s);
#pragma unroll
    for (int ib = 0; ib < 4; ++ib) {
      int j = c + 16 * ib;
      int p = j & (M - 1);
      int jb = j >> (6 - 2 * s);
      int base = jb * (M << 2) + p;
      bfly4_dif(sr, si, twr, twi, base * 17 + xi, (base + M) * 17 + xi,
                (base + 2 * M) * 17 + xi, (base + 3 * M) * 17 + xi,
                (p * F) & 255, (2 * p * F) & 255, (3 * p * F) & 255);
    }
    __syncthreads();
  }
#pragma unroll
  for (int i = 0; i < 16; ++i) {
    int e = c * 16 + i;
    Gp[(size_t)e << 8] = make_float2(sr[e * 17 + xi], si[e * 17 + xi]);
  }
}

// ---- Pass 3: radix-4 DIF FFT along x on Gx and Gy tiles (same location),
// then local products + shell reduce. No mirror: weight 2 for kz in 1..127.
// Block: 512 threads = 2 tiles x (8 rows x 256 x).
__global__ __launch_bounds__(512) void fft_x_reduce(const float2* __restrict__ G,
                                                    double* __restrict__ sums) {
  __shared__ float Axr[256 * 9], Axi[256 * 9], Ayr[256 * 9], Ayi[256 * 9]; // [slot*9 + row]
  __shared__ float twr[256], twi[256];
  __shared__ float sh[3 * SBINS];
  int t = threadIdx.x;
  fill_tw(twr, twi, t);
  for (int i = t; i < 3 * SBINS; i += 512) sh[i] = 0.f;
  int vol = t >> 8, tt = t & 255;
  int li = tt >> 5, c = tt & 31;     // row 0..7, col 0..31
  int kz = blockIdx.y;
  int r0 = blockIdx.x << 3;
  const float2* Gp = G + (size_t)vol * VSTRIDE + ((size_t)kz << 16) + ((size_t)(r0 + li) << 8);
  float* pr = vol ? Ayr : Axr;
  float* pi = vol ? Ayi : Axi;
#pragma unroll
  for (int it = 0; it < 8; ++it) {
    int e = c + 32 * it;
    float2 v = Gp[e];
    pr[e * 9 + li] = v.x;
    pi[e * 9 + li] = v.y;
  }
  __syncthreads();
#pragma unroll
  for (int s = 0; s < 4; ++s) {
    int M = 64 >> (2 * s);
    int F = 1 << (2 * s);
#pragma unroll
    for (int ib = 0; ib < 2; ++ib) {
      int j = c + 32 * ib;
      int p = j & (M - 1);
      int jb = j >> (6 - 2 * s);
      int base = jb * (M << 2) + p;
      bfly4_dif(pr, pi, twr, twi, base * 9 + li, (base + M) * 9 + li,
                (base + 2 * M) * 9 + li, (base + 3 * M) * 9 + li,
                (p * F) & 255, (2 * p * F) & 255, (3 * p * F) & 255);
    }
    __syncthreads();
  }
  int fz = kz - ((kz & 128) ? 256 : 0);
  int fz2 = fz * fz;
  float wf = (kz == 0 || kz == 128) ? 1.f : 2.f;
#pragma unroll
  for (int it = 0; it < 4; ++it) {
    int v = t + 512 * it;            // 2048 voxels per block
    int e = v & 255, lr = v >> 8;
    int kx = rev4(e);
    int ky = rev4(r0 + lr);
    int fx = kx - ((kx & 128) ? 256 : 0);
    int fy = ky - ((ky & 128) ? 256 : 0);
    int m = fx * fx + fy * fy + fz2;
    int sb = (int)sqrtf((float)m);
    while (sb * sb > m) --sb;
    while ((sb + 1) * (sb + 1) <= m) ++sb;
    int a = e * 9 + lr;
    float xr = Axr[a], xi = Axi[a], yr = Ayr[a], yi = Ayi[a];
    atomicAdd(&sh[3 * sb + 0], wf * (xr * yr + xi * yi));
    atomicAdd(&sh[3 * sb + 1], wf * (xr * xr + xi * xi));
    atomicAdd(&sh[3 * sb + 2], wf * (yr * yr + yi * yi));
  }
  __syncthreads();
  for (int i = t; i < 3 * SBINS; i += 512) {
    float vv = sh[i];
    if (vv != 0.f) atomicAdd(&sums[i], (double)vv);
  }
}

__global__ void finalize(const double* __restrict__ sums, float* __restrict__ out) {
  if (threadIdx.x == 0 && blockIdx.x == 0) {
    double acc = 0.0;
    for (int b = 0; b < 2; ++b) {
      const double* s = sums + b * 3 * SBINS;
      for (int k = 0; k < NSHELL; ++k)
        acc += s[3 * k] / sqrt(s[3 * k + 1] * s[3 * k + 2] + 1e-8);
    }
    out[0] = (float)(acc / (2.0 * (double)NSHELL));
  }
}

extern "C" void kernel_launch(void* const* d_in, const int* in_sizes, int n_in,
                              void* d_out, int out_size, void* d_ws, size_t ws_size,
                              hipStream_t stream) {
  const float* X = (const float*)d_in[0];
  const float* Y = (const float*)d_in[1];
  float2* Gx = (float2*)d_ws;                 // 129 planes
  float2* Gy = Gx + VSTRIDE;                  // 129 planes
  double* sums = (double*)((char*)d_ws + (size_t)2 * VSTRIDE * sizeof(float2));

  hipMemsetAsync(sums, 0, 2 * 3 * SBINS * sizeof(double), stream);

  for (int b = 0; b < 2; ++b) {
    fft_z_pack<<<4096, 256, 0, stream>>>(X + (size_t)b * VOL, Y + (size_t)b * VOL, Gx, Gy);
    fft_y<<<dim3(16, 129, 2), 256, 0, stream>>>(Gx);     // Gx base; z selects Gx/Gy
    fft_x_reduce<<<dim3(32, 129), 512, 0, stream>>>(Gx, sums + b * 3 * SBINS);
  }
  finalize<<<1, 1, 0, stream>>>(sums, (float*)d_out);
}

// Round 4
// 711.836 us; speedup vs baseline: 1.7831x; 1.2347x over previous
//
#include <hip/hip_runtime.h>
#include <math.h>

#define VOL (256 * 256 * 256)
#define NSHELL 222
#define SBINS 224
#define PI_D 3.14159265358979323846
#define VSTRIDE ((size_t)129 << 16)   // one half-volume: 129 planes of 256x256 float2

// base-4 digit reversal of an 8-bit index (self-inverse)
__device__ __forceinline__ int rev4(int e) {
  return ((e & 3) << 6) | (((e >> 2) & 3) << 4) | (((e >> 4) & 3) << 2) | ((e >> 6) & 3);
}

// one-time twiddle table: gtw[k] = exp(-2*pi*i*k/256), f64-accurate
__global__ void tw_init(float2* __restrict__ gtw) {
  int t = threadIdx.x;
  double a = -2.0 * PI_D * (double)t / 256.0;
  gtw[t] = make_float2((float)cos(a), (float)sin(a));
}

// radix-4 DIF butterfly, in-place on 4 LDS slots; twiddles applied on outputs.
__device__ __forceinline__ void bfly4_dif(float* re, float* im, const float* twr,
                                          const float* twi, int a0, int a1, int a2,
                                          int a3, int t1, int t2, int t3) {
  float x0r = re[a0], x0i = im[a0], x1r = re[a1], x1i = im[a1];
  float x2r = re[a2], x2i = im[a2], x3r = re[a3], x3i = im[a3];
  float s02r = x0r + x2r, s02i = x0i + x2i, d02r = x0r - x2r, d02i = x0i - x2i;
  float s13r = x1r + x3r, s13i = x1i + x3i, d13r = x1r - x3r, d13i = x1i - x3i;
  re[a0] = s02r + s13r; im[a0] = s02i + s13i;
  float c1r = d02r + d13i, c1i = d02i - d13r;          // d02 - i*d13
  re[a1] = c1r * twr[t1] - c1i * twi[t1]; im[a1] = c1r * twi[t1] + c1i * twr[t1];
  float c2r = s02r - s13r, c2i = s02i - s13i;
  re[a2] = c2r * twr[t2] - c2i * twi[t2]; im[a2] = c2r * twi[t2] + c2i * twr[t2];
  float c3r = d02r - d13i, c3i = d02i + d13r;          // d02 + i*d13
  re[a3] = c3r * twr[t3] - c3i * twi[t3]; im[a3] = c3r * twi[t3] + c3i * twr[t3];
}

// wave-level segmented reduce + flush: bins nondecreasing across lanes.
__device__ __forceinline__ void seg_flush(float* sh, int sb, float nv, float pv,
                                          float qv, int l) {
#pragma unroll
  for (int d = 1; d < 64; d <<= 1) {
    int sbo = __shfl_down(sb, d);
    float no = __shfl_down(nv, d);
    float po = __shfl_down(pv, d);
    float qo = __shfl_down(qv, d);
    if (l + d < 64 && sbo == sb) { nv += no; pv += po; qv += qo; }
  }
  int sbp = __shfl_up(sb, 1);
  if (l == 0 || sbp != sb) {
    atomicAdd(&sh[3 * sb + 0], nv);
    atomicAdd(&sh[3 * sb + 1], pv);
    atomicAdd(&sh[3 * sb + 2], qv);
  }
}

// ---- Pass 1: pack Z = X + iY, radix-4 DIF FFT along z, Hermitian unpack ----
__global__ __launch_bounds__(256) void fft_z_pack(const float* __restrict__ X,
                                                  const float* __restrict__ Y,
                                                  float2* __restrict__ Gx,
                                                  float2* __restrict__ Gy,
                                                  const float2* __restrict__ gtw) {
  __shared__ float zr[256 * 17], zi[256 * 17];   // [slot*17 + line]
  __shared__ float twr[256], twi[256];
  int t = threadIdx.x;
  { float2 w = gtw[t]; twr[t] = w.x; twi[t] = w.y; }
  int li = t >> 4, c = t & 15;
  int y = blockIdx.x >> 4;
  int x0 = (blockIdx.x & 15) << 4;
  const float4* xp = (const float4*)(X + (((size_t)(x0 + li)) << 16) + ((size_t)y << 8));
  const float4* yp = (const float4*)(Y + (((size_t)(x0 + li)) << 16) + ((size_t)y << 8));
#pragma unroll
  for (int it = 0; it < 4; ++it) {
    int e4 = c + 16 * it;
    float4 a = xp[e4];
    float4 b = yp[e4];
    int e = e4 << 2;
    zr[(e + 0) * 17 + li] = a.x; zi[(e + 0) * 17 + li] = b.x;
    zr[(e + 1) * 17 + li] = a.y; zi[(e + 1) * 17 + li] = b.y;
    zr[(e + 2) * 17 + li] = a.z; zi[(e + 2) * 17 + li] = b.z;
    zr[(e + 3) * 17 + li] = a.w; zi[(e + 3) * 17 + li] = b.w;
  }
  __syncthreads();
#pragma unroll
  for (int s = 0; s < 4; ++s) {
    int M = 64 >> (2 * s);
    int F = 1 << (2 * s);
#pragma unroll
    for (int ib = 0; ib < 4; ++ib) {
      int j = c + 16 * ib;
      int p = j & (M - 1);
      int jb = j >> (6 - 2 * s);
      int base = jb * (M << 2) + p;
      bfly4_dif(zr, zi, twr, twi, base * 17 + li, (base + M) * 17 + li,
                (base + 2 * M) * 17 + li, (base + 3 * M) * 17 + li,
                (p * F) & 255, (2 * p * F) & 255, (3 * p * F) & 255);
    }
    __syncthreads();
  }
  int krow = t >> 4, xi = t & 15;
#pragma unroll
  for (int g = 0; g < 9; ++g) {
    int kz = g * 16 + krow;
    if (kz <= 128) {
      int s1 = rev4(kz & 255);
      int s2 = rev4((256 - kz) & 255);
      float ar = zr[s1 * 17 + xi], ai = zi[s1 * 17 + xi];
      float br = zr[s2 * 17 + xi], bi = zi[s2 * 17 + xi];
      size_t off = ((size_t)kz << 16) + ((size_t)y << 8) + (size_t)(x0 + xi);
      Gx[off] = make_float2(0.5f * (ar + br), 0.5f * (ai - bi));
      Gy[off] = make_float2(0.5f * (ai + bi), 0.5f * (br - ar));
    }
  }
}

// ---- Pass 2: radix-4 DIF FFT along y; row r ends holding ky = rev4(r) ----
__global__ __launch_bounds__(256) void fft_y(float2* __restrict__ G,
                                             const float2* __restrict__ gtw) {
  __shared__ float sr[256 * 17], si[256 * 17];   // [slot*17 + xi]
  __shared__ float twr[256], twi[256];
  int t = threadIdx.x;
  { float2 w = gtw[t]; twr[t] = w.x; twi[t] = w.y; }
  int xi = t & 15, c = t >> 4;
  int x0 = blockIdx.x << 4;
  int kz = blockIdx.y;
  float2* Gp = G + (size_t)blockIdx.z * VSTRIDE + ((size_t)kz << 16) + (size_t)(x0 + xi);
#pragma unroll
  for (int i = 0; i < 16; ++i) {
    int e = c * 16 + i;
    float2 v = Gp[(size_t)e << 8];
    sr[e * 17 + xi] = v.x;
    si[e * 17 + xi] = v.y;
  }
  __syncthreads();
#pragma unroll
  for (int s = 0; s < 4; ++s) {
    int M = 64 >> (2 * s);
    int F = 1 << (2 * s);
#pragma unroll
    for (int ib = 0; ib < 4; ++ib) {
      int j = c + 16 * ib;
      int p = j & (M - 1);
      int jb = j >> (6 - 2 * s);
      int base = jb * (M << 2) + p;
      bfly4_dif(sr, si, twr, twi, base * 17 + xi, (base + M) * 17 + xi,
                (base + 2 * M) * 17 + xi, (base + 3 * M) * 17 + xi,
                (p * F) & 255, (2 * p * F) & 255, (3 * p * F) & 255);
    }
    __syncthreads();
  }
#pragma unroll
  for (int i = 0; i < 16; ++i) {
    int e = c * 16 + i;
    Gp[(size_t)e << 8] = make_float2(sr[e * 17 + xi], si[e * 17 + xi]);
  }
}

// ---- Pass 3: x-FFT (natural-order output) + paired products + segmented reduce ----
__global__ __launch_bounds__(512) void fft_x_reduce(const float2* __restrict__ G,
                                                    double* __restrict__ sums,
                                                    const float2* __restrict__ gtw) {
  __shared__ float Axr[256 * 9], Axi[256 * 9], Ayr[256 * 9], Ayi[256 * 9]; // [slot*9 + row]
  __shared__ float twr[256], twi[256];
  __shared__ float sh[3 * SBINS];
  int t = threadIdx.x;
  if (t < 256) { float2 w = gtw[t]; twr[t] = w.x; twi[t] = w.y; }
  for (int i = t; i < 3 * SBINS; i += 512) sh[i] = 0.f;
  int vol = t >> 8, tt = t & 255;
  int li = tt >> 5, c = tt & 31;     // row 0..7, col 0..31
  int kz = blockIdx.y;
  int r0 = blockIdx.x << 3;
  const float2* Gp = G + (size_t)vol * VSTRIDE + ((size_t)kz << 16) + ((size_t)(r0 + li) << 8);
  float* pr = vol ? Ayr : Axr;
  float* pi = vol ? Ayi : Axi;
#pragma unroll
  for (int it = 0; it < 8; ++it) {
    int e = c + 32 * it;
    float2 v = Gp[e];
    pr[e * 9 + li] = v.x;
    pi[e * 9 + li] = v.y;
  }
  __syncthreads();
#pragma unroll
  for (int s = 0; s < 3; ++s) {
    int M = 64 >> (2 * s);
    int F = 1 << (2 * s);
#pragma unroll
    for (int ib = 0; ib < 2; ++ib) {
      int j = c + 32 * ib;
      int p = j & (M - 1);
      int jb = j >> (6 - 2 * s);
      int base = jb * (M << 2) + p;
      bfly4_dif(pr, pi, twr, twi, base * 9 + li, (base + M) * 9 + li,
                (base + 2 * M) * 9 + li, (base + 3 * M) * 9 + li,
                (p * F) & 255, (2 * p * F) & 255, (3 * p * F) & 255);
    }
    __syncthreads();
  }
  // stage 3: p=0 (twiddle-free); stash, sync, write digit-reversed -> natural kx
  float or_[2][4], oi_[2][4];
#pragma unroll
  for (int ib = 0; ib < 2; ++ib) {
    int j = c + 32 * ib;
    int base = 4 * j;
    float x0r = pr[(base + 0) * 9 + li], x0i = pi[(base + 0) * 9 + li];
    float x1r = pr[(base + 1) * 9 + li], x1i = pi[(base + 1) * 9 + li];
    float x2r = pr[(base + 2) * 9 + li], x2i = pi[(base + 2) * 9 + li];
    float x3r = pr[(base + 3) * 9 + li], x3i = pi[(base + 3) * 9 + li];
    float s02r = x0r + x2r, s02i = x0i + x2i, d02r = x0r - x2r, d02i = x0i - x2i;
    float s13r = x1r + x3r, s13i = x1i + x3i, d13r = x1r - x3r, d13i = x1i - x3i;
    or_[ib][0] = s02r + s13r; oi_[ib][0] = s02i + s13i;
    or_[ib][1] = d02r + d13i; oi_[ib][1] = d02i - d13r;
    or_[ib][2] = s02r - s13r; oi_[ib][2] = s02i - s13i;
    or_[ib][3] = d02r - d13i; oi_[ib][3] = d02i + d13r;
  }
  __syncthreads();
#pragma unroll
  for (int ib = 0; ib < 2; ++ib) {
    int j = c + 32 * ib;
#pragma unroll
    for (int q = 0; q < 4; ++q) {
      int slot = (q << 6) | ((j & 3) << 4) | (((j >> 2) & 3) << 2) | (j >> 4); // rev4(4j+q)
      pr[slot * 9 + li] = or_[ib][q];
      pi[slot * 9 + li] = oi_[ib][q];
    }
  }
  __syncthreads();
  int fz = kz - ((kz & 128) ? 256 : 0);
  int fz2 = fz * fz;
  {
    int w = t >> 6, l = t & 63;      // wave w <-> row w
    int ky = rev4(r0 + w);
    int fy = ky - ((ky & 128) ? 256 : 0);
    int c2 = fy * fy + fz2;
#pragma unroll
    for (int pass = 0; pass < 2; ++pass) {
      int kx = pass * 64 + l;
      int a = kx * 9 + w;
      float xr = Axr[a], xi = Axi[a], yr = Ayr[a], yi = Ayi[a];
      float nv = xr * yr + xi * yi;
      float pv = xr * xr + xi * xi;
      float qv = yr * yr + yi * yi;
      if (kx != 0) {
        int ma = ((256 - kx) & 255) * 9 + w;
        float mxr = Axr[ma], mxi = Axi[ma], myr = Ayr[ma], myi = Ayi[ma];
        nv += mxr * myr + mxi * myi;
        pv += mxr * mxr + mxi * mxi;
        qv += myr * myr + myi * myi;
      }
      int m = kx * kx + c2;
      int sb = (int)sqrtf((float)m);
      while (sb * sb > m) --sb;
      while ((sb + 1) * (sb + 1) <= m) ++sb;
      seg_flush(sh, sb, nv, pv, qv, l);
    }
    if (l == 0) {                     // kx = 128 (self-mirrored)
      int a = 128 * 9 + w;
      float xr = Axr[a], xi = Axi[a], yr = Ayr[a], yi = Ayi[a];
      int m = 16384 + c2;
      int sb = (int)sqrtf((float)m);
      while (sb * sb > m) --sb;
      while ((sb + 1) * (sb + 1) <= m) ++sb;
      atomicAdd(&sh[3 * sb + 0], xr * yr + xi * yi);
      atomicAdd(&sh[3 * sb + 1], xr * xr + xi * xi);
      atomicAdd(&sh[3 * sb + 2], yr * yr + yi * yi);
    }
  }
  __syncthreads();
  float wf = (kz == 0 || kz == 128) ? 1.f : 2.f;   // kz-plane Hermitian weight
  for (int i = t; i < 3 * SBINS; i += 512) {
    float vv = sh[i];
    if (vv != 0.f) atomicAdd(&sums[i], (double)(wf * vv));
  }
}

__global__ void finalize(const double* __restrict__ sums, float* __restrict__ out) {
  if (threadIdx.x == 0 && blockIdx.x == 0) {
    double acc = 0.0;
    for (int b = 0; b < 2; ++b) {
      const double* s = sums + b * 3 * SBINS;
      for (int k = 0; k < NSHELL; ++k)
        acc += s[3 * k] / sqrt(s[3 * k + 1] * s[3 * k + 2] + 1e-8);
    }
    out[0] = (float)(acc / (2.0 * (double)NSHELL));
  }
}

extern "C" void kernel_launch(void* const* d_in, const int* in_sizes, int n_in,
                              void* d_out, int out_size, void* d_ws, size_t ws_size,
                              hipStream_t stream) {
  const float* X = (const float*)d_in[0];
  const float* Y = (const float*)d_in[1];
  float2* Gx = (float2*)d_ws;                 // 129 planes
  float2* Gy = Gx + VSTRIDE;                  // 129 planes
  double* sums = (double*)((char*)d_ws + (size_t)2 * VSTRIDE * sizeof(float2));
  float2* gtw = (float2*)(sums + 2 * 3 * SBINS);

  hipMemsetAsync(sums, 0, 2 * 3 * SBINS * sizeof(double), stream);
  tw_init<<<1, 256, 0, stream>>>(gtw);

  for (int b = 0; b < 2; ++b) {
    fft_z_pack<<<4096, 256, 0, stream>>>(X + (size_t)b * VOL, Y + (size_t)b * VOL, Gx, Gy, gtw);
    fft_y<<<dim3(16, 129, 2), 256, 0, stream>>>(Gx, gtw);
    fft_x_reduce<<<dim3(32, 129), 512, 0, stream>>>(Gx, sums + b * 3 * SBINS, gtw);
  }
  finalize<<<1, 1, 0, stream>>>(sums, (float*)d_out);
}